// Round 1
// baseline (4118.806 us; speedup 1.0000x reference)
//
#include <hip/hip_runtime.h>
#include <hip/hip_bf16.h>

#define NLVL   20
#define PN     5000
#define EPLE   40000
#define FDIM   128
#define HDIM   256
#define CAP    32
#define TM     20
#define RT     5          // rows per thread  (ty: 4 groups * 5 rows)
#define CT     4          // cols per thread  (tx: 64 groups * 4 cols)

// ---------------- CSR-lite build (fixed-capacity buckets) ----------------
__global__ void fill_csr_kernel(const int* __restrict__ esrc,
                                const int* __restrict__ edst,
                                int* __restrict__ counts,
                                int* __restrict__ buckets) {
  int e = blockIdx.x * 256 + threadIdx.x;
  if (e >= (NLVL - 1) * EPLE) return;
  int l = e / EPLE;
  int key = l * PN + edst[e];
  int pos = atomicAdd(&counts[key], 1);
  if (pos < CAP) buckets[key * CAP + pos] = esrc[e];   // esrc already global ids
}

// ---------------- embed: base = tanh(nf @ W_embed + b) ----------------
__global__ __launch_bounds__(256, 2) void embed_kernel(
    const float* __restrict__ nf, const float* __restrict__ W,
    const float* __restrict__ b, float* __restrict__ out) {
  __shared__ float fl[TM * FDIM];
  const int tid = threadIdx.x;
  const int tx = tid & 63, ty = tid >> 6;
  const int row0 = blockIdx.x * TM;

  const float4* src = (const float4*)(nf + (size_t)row0 * FDIM);
  float4* dstv = (float4*)fl;
  for (int i = tid; i < TM * FDIM / 4; i += 256) dstv[i] = src[i];
  __syncthreads();

  float acc[RT][CT];
  float4 bv = *(const float4*)(b + 4 * tx);
  #pragma unroll
  for (int r = 0; r < RT; ++r) { acc[r][0]=bv.x; acc[r][1]=bv.y; acc[r][2]=bv.z; acc[r][3]=bv.w; }

  for (int k = 0; k < FDIM; k += 4) {
    float a[RT][4];
    #pragma unroll
    for (int r = 0; r < RT; ++r) {
      float4 av = *(const float4*)(&fl[(ty * RT + r) * FDIM + k]);
      a[r][0]=av.x; a[r][1]=av.y; a[r][2]=av.z; a[r][3]=av.w;
    }
    #pragma unroll
    for (int kk = 0; kk < 4; ++kk) {
      float4 wv = *(const float4*)(W + (size_t)(k + kk) * HDIM + 4 * tx);
      #pragma unroll
      for (int r = 0; r < RT; ++r) {
        acc[r][0] = fmaf(a[r][kk], wv.x, acc[r][0]);
        acc[r][1] = fmaf(a[r][kk], wv.y, acc[r][1]);
        acc[r][2] = fmaf(a[r][kk], wv.z, acc[r][2]);
        acc[r][3] = fmaf(a[r][kk], wv.w, acc[r][3]);
      }
    }
  }
  #pragma unroll
  for (int r = 0; r < RT; ++r) {
    float4 o;
    o.x = tanhf(acc[r][0]); o.y = tanhf(acc[r][1]);
    o.z = tanhf(acc[r][2]); o.w = tanhf(acc[r][3]);
    *(float4*)(out + (size_t)(row0 + ty * RT + r) * HDIM + 4 * tx) = o;
  }
}

// ---------------- fused per-level MLP helpers ----------------
__device__ __forceinline__ void accum_gemm(const float* __restrict__ in_lds,
    const float* __restrict__ Wg, float acc[RT][CT], int tx, int ty) {
  for (int k = 0; k < HDIM; k += 4) {
    float a[RT][4];
    #pragma unroll
    for (int r = 0; r < RT; ++r) {
      float4 av = *(const float4*)(in_lds + (ty * RT + r) * HDIM + k);
      a[r][0]=av.x; a[r][1]=av.y; a[r][2]=av.z; a[r][3]=av.w;
    }
    #pragma unroll
    for (int kk = 0; kk < 4; ++kk) {
      float4 wv = *(const float4*)(Wg + (k + kk) * HDIM + 4 * tx);
      #pragma unroll
      for (int r = 0; r < RT; ++r) {
        acc[r][0] = fmaf(a[r][kk], wv.x, acc[r][0]);
        acc[r][1] = fmaf(a[r][kk], wv.y, acc[r][1]);
        acc[r][2] = fmaf(a[r][kk], wv.z, acc[r][2]);
        acc[r][3] = fmaf(a[r][kk], wv.w, acc[r][3]);
      }
    }
  }
}

__device__ __forceinline__ void init_bias(float acc[RT][CT], const float* __restrict__ bg, int tx) {
  float4 bv = *(const float4*)(bg + 4 * tx);
  #pragma unroll
  for (int r = 0; r < RT; ++r) { acc[r][0]=bv.x; acc[r][1]=bv.y; acc[r][2]=bv.z; acc[r][3]=bv.w; }
}

__device__ __forceinline__ void store_relu_lds(float acc[RT][CT], float* __restrict__ out_lds,
                                               int tx, int ty) {
  #pragma unroll
  for (int r = 0; r < RT; ++r) {
    float4 o;
    o.x = fmaxf(acc[r][0], 0.f); o.y = fmaxf(acc[r][1], 0.f);
    o.z = fmaxf(acc[r][2], 0.f); o.w = fmaxf(acc[r][3], 0.f);
    *(float4*)(out_lds + (ty * RT + r) * HDIM + 4 * tx) = o;
  }
}

__device__ __forceinline__ void gemm256(const float* __restrict__ in_lds,
    const float* __restrict__ Wg, const float* __restrict__ bg,
    float* __restrict__ out_lds, int tx, int ty) {
  float acc[RT][CT];
  init_bias(acc, bg, tx);
  accum_gemm(in_lds, Wg, acc, tx, ty);
  store_relu_lds(acc, out_lds, tx, ty);
}

__device__ __forceinline__ void gemm512(const float* __restrict__ in_first,
    const float* __restrict__ in_second, const float* __restrict__ Wg,
    const float* __restrict__ bg, float* __restrict__ out_lds, int tx, int ty) {
  float acc[RT][CT];
  init_bias(acc, bg, tx);
  accum_gemm(in_first,  Wg,               acc, tx, ty);   // k = 0..255  (base)
  accum_gemm(in_second, Wg + HDIM * HDIM, acc, tx, ty);   // k = 256..511 (mr)
  store_relu_lds(acc, out_lds, tx, ty);
}

__device__ __forceinline__ void gemm256_store_global(const float* __restrict__ in_lds,
    const float* __restrict__ Wg, const float* __restrict__ bg,
    float* __restrict__ out_g, int tx, int ty) {
  float acc[RT][CT];
  init_bias(acc, bg, tx);
  accum_gemm(in_lds, Wg, acc, tx, ty);
  #pragma unroll
  for (int r = 0; r < RT; ++r) {
    float4 o;
    o.x = fmaxf(acc[r][0], 0.f); o.y = fmaxf(acc[r][1], 0.f);
    o.z = fmaxf(acc[r][2], 0.f); o.w = fmaxf(acc[r][3], 0.f);
    *(float4*)(out_g + (size_t)(ty * RT + r) * HDIM + 4 * tx) = o;
  }
}

__device__ __forceinline__ void add_bufs(float* __restrict__ dst,
    const float* __restrict__ a, const float* __restrict__ b, int tid) {
  for (int i = tid; i < TM * HDIM / 4; i += 256) {
    float4 x = ((const float4*)a)[i], y = ((const float4*)b)[i];
    ((float4*)dst)[i] = make_float4(x.x+y.x, x.y+y.y, x.z+y.z, x.w+y.w);
  }
}

// ---------------- one fused kernel per level ----------------
__global__ __launch_bounds__(256, 2) void level_kernel(
    float* __restrict__ embeds,
    const int* __restrict__ counts, const int* __restrict__ buckets,
    const float* __restrict__ mp_w, const float* __restrict__ mp_b,
    const float* __restrict__ ne_w0, const float* __restrict__ ne_b0,
    const float* __restrict__ ne_w, const float* __restrict__ ne_b,
    int l) {
  __shared__ float A[TM * HDIM];
  __shared__ float B[TM * HDIM];
  __shared__ float C[TM * HDIM];
  __shared__ int cnt_s[TM];
  const int tid = threadIdx.x;
  const int tx = tid & 63, ty = tid >> 6;
  const int p0 = blockIdx.x * TM;

  if (tid < TM) cnt_s[tid] = min(counts[l * PN + p0 + tid], CAP);
  __syncthreads();

  // gather mailbox (segment sum) -> A
  {
    float ac[RT][4];
    #pragma unroll
    for (int r = 0; r < RT; ++r) { ac[r][0]=0.f; ac[r][1]=0.f; ac[r][2]=0.f; ac[r][3]=0.f; }
    int mymax = 0;
    #pragma unroll
    for (int r = 0; r < RT; ++r) mymax = max(mymax, cnt_s[ty * RT + r]);
    for (int j = 0; j < mymax; ++j) {
      #pragma unroll
      for (int r = 0; r < RT; ++r) {
        if (j < cnt_s[ty * RT + r]) {
          int s = buckets[(l * PN + p0 + ty * RT + r) * CAP + j];
          float4 v = *(const float4*)(embeds + (size_t)s * HDIM + 4 * tx);
          ac[r][0]+=v.x; ac[r][1]+=v.y; ac[r][2]+=v.z; ac[r][3]+=v.w;
        }
      }
    }
    #pragma unroll
    for (int r = 0; r < RT; ++r)
      *(float4*)(A + (ty*RT+r)*HDIM + 4*tx) = make_float4(ac[r][0],ac[r][1],ac[r][2],ac[r][3]);
  }
  __syncthreads();

  // redux chain: t0,u1,u2,u3(mr)
  gemm256(A, mp_w + 0*HDIM*HDIM, mp_b + 0*HDIM, B, tx, ty); __syncthreads();  // t0 -> B
  gemm256(B, mp_w + 1*HDIM*HDIM, mp_b + 1*HDIM, C, tx, ty); __syncthreads();  // u1 -> C
  add_bufs(A, B, C, tid); __syncthreads();                                    // A = t0+u1
  gemm256(A, mp_w + 2*HDIM*HDIM, mp_b + 2*HDIM, B, tx, ty); __syncthreads();  // u2 -> B
  add_bufs(C, C, B, tid); __syncthreads();                                    // C = u1+u2
  gemm256(C, mp_w + 3*HDIM*HDIM, mp_b + 3*HDIM, A, tx, ty); __syncthreads();  // mr -> A

  // base rows of level l+1 -> B
  {
    const float4* src = (const float4*)(embeds + (size_t)((l + 1) * PN + p0) * HDIM);
    float4* dstv = (float4*)B;
    for (int i = tid; i < TM * HDIM / 4; i += 256) dstv[i] = src[i];
  }
  __syncthreads();

  // apply chain: x0 = relu([base|mr] @ ne_w0 + ne_b0), then resid tail
  gemm512(B, A, ne_w0, ne_b0, C, tx, ty); __syncthreads();                    // x0 -> C
  gemm256(C, ne_w + 0*HDIM*HDIM, ne_b + 0*HDIM, B, tx, ty); __syncthreads(); // v1 -> B
  add_bufs(A, C, B, tid); __syncthreads();                                    // A = x0+v1
  gemm256(A, ne_w + 1*HDIM*HDIM, ne_b + 1*HDIM, C, tx, ty); __syncthreads(); // v2 -> C
  add_bufs(B, B, C, tid); __syncthreads();                                    // B = v1+v2
  gemm256_store_global(B, ne_w + 2*HDIM*HDIM, ne_b + 2*HDIM,
                       embeds + (size_t)((l + 1) * PN + p0) * HDIM, tx, ty);  // out
}

// ---------------- launch ----------------
extern "C" void kernel_launch(void* const* d_in, const int* in_sizes, int n_in,
                              void* d_out, int out_size, void* d_ws, size_t ws_size,
                              hipStream_t stream) {
  (void)in_sizes; (void)n_in; (void)out_size; (void)ws_size;
  const float* nf      = (const float*)d_in[0];
  const float* W_embed = (const float*)d_in[1];
  const float* b_embed = (const float*)d_in[2];
  const float* mp_w    = (const float*)d_in[3];
  const float* mp_b    = (const float*)d_in[4];
  const float* ne_w0   = (const float*)d_in[5];
  const float* ne_b0   = (const float*)d_in[6];
  const float* ne_w    = (const float*)d_in[7];
  const float* ne_b    = (const float*)d_in[8];
  const int*   esrc    = (const int*)d_in[9];
  const int*   edst    = (const int*)d_in[10];
  float* out = (float*)d_out;

  int* counts  = (int*)d_ws;                                   // 19*5000 ints
  int* buckets = (int*)((char*)d_ws + (512 << 10));            // 19*5000*CAP ints (~12.2 MB)

  hipMemsetAsync(counts, 0, (NLVL - 1) * PN * sizeof(int), stream);
  fill_csr_kernel<<<((NLVL - 1) * EPLE + 255) / 256, 256, 0, stream>>>(esrc, edst, counts, buckets);
  embed_kernel<<<(NLVL * PN) / TM, 256, 0, stream>>>(nf, W_embed, b_embed, out);
  for (int l = 0; l < NLVL - 1; ++l) {
    level_kernel<<<PN / TM, 256, 0, stream>>>(out, counts, buckets,
                                              mp_w, mp_b, ne_w0, ne_b0, ne_w, ne_b, l);
  }
}

// Round 2
// 3290.034 us; speedup vs baseline: 1.2519x; 1.2519x over previous
//
#include <hip/hip_runtime.h>
#include <hip/hip_bf16.h>

#define NLVL 20
#define PN   5000
#define EPLE 40000
#define FDIM 128
#define HDIM 256
#define NTOT (NLVL * PN)
#define CAP  32

typedef __attribute__((ext_vector_type(8))) short short8;   // 8 bf16 in 4 VGPRs
typedef __attribute__((ext_vector_type(4))) float f32x4;

__device__ __forceinline__ f32x4 mfma16(short8 a, short8 b, f32x4 c) {
  return __builtin_amdgcn_mfma_f32_16x16x32_bf16(a, b, c, 0, 0, 0);
}

__device__ __forceinline__ ushort f2b(float f) {
  union { float f; unsigned u; } v; v.f = f;
  unsigned r = v.u + 0x7FFFu + ((v.u >> 16) & 1u);   // RNE
  return (ushort)(r >> 16);
}

__device__ __forceinline__ short8 pack8(const float* v) {
  short8 o;
  #pragma unroll
  for (int i = 0; i < 8; ++i) o[i] = (short)f2b(v[i]);
  return o;
}

__device__ __forceinline__ f32x4 relu4(f32x4 a) {
  f32x4 o;
  o[0] = fmaxf(a[0], 0.f); o[1] = fmaxf(a[1], 0.f);
  o[2] = fmaxf(a[2], 0.f); o[3] = fmaxf(a[3], 0.f);
  return o;
}

// ---- LDS act buffer: per-wave [16 rows][256 cols] bf16, XOR-swizzled -------
// write: lane holds (row r, 4 consecutive cols 16cc+4g..+3)  -> 8B store
// read : B-frag kc = (row r, cols kc*32+8g..+7)              -> 16B load
__device__ __forceinline__ void wact(char* sb, int r, int g, int cc, f32x4 v) {
  union { uint2 u2; ushort s[4]; } p;
  p.s[0] = f2b(v[0]); p.s[1] = f2b(v[1]); p.s[2] = f2b(v[2]); p.s[3] = f2b(v[3]);
  *(uint2*)(sb + r * 512 + ((32 * cc + 8 * g) ^ ((r & 7) << 4))) = p.u2;
}
__device__ __forceinline__ short8 ract(const char* sb, int r, int g, int kc) {
  return *(const short8*)(sb + r * 512 + ((64 * kc + 16 * g) ^ ((r & 7) << 4)));
}
__device__ __forceinline__ void w1(char* sb, int r, int g, const f32x4* X) {
  #pragma unroll
  for (int cc = 0; cc < 16; ++cc) wact(sb, r, g, cc, X[cc]);
}
__device__ __forceinline__ void w2(char* sb, int r, int g, const f32x4* X, const f32x4* Y) {
  #pragma unroll
  for (int cc = 0; cc < 16; ++cc) wact(sb, r, g, cc, X[cc] + Y[cc]);
}
__device__ __forceinline__ void rB(const char* sb, int r, int g, short8* B) {
  #pragma unroll
  for (int kc = 0; kc < 8; ++kc) B[kc] = ract(sb, r, g, kc);
}

// A-operand (weights, pre-transposed [N][K] bf16): lane = (Wt row 16cc+r, k=kc*32+8g..+7)
__device__ __forceinline__ short8 ldw16(const ushort* __restrict__ Wt, int sK,
                                        int cc, int kc, int r, int g) {
  return *(const short8*)(Wt + (16 * cc + r) * sK + kc * 32 + 8 * g);
}

template <int NK>
__device__ __forceinline__ void stage(const ushort* __restrict__ Wt, int sK,
                                      const float* __restrict__ bias,
                                      const short8* B, f32x4* out, int r, int g) {
  #pragma unroll
  for (int cc = 0; cc < 16; ++cc) {
    f32x4 acc = *(const f32x4*)(bias + 16 * cc + 4 * g);
    #pragma unroll
    for (int kc = 0; kc < NK; ++kc)
      acc = mfma16(ldw16(Wt, sK, cc, kc, r, g), B[kc], acc);
    out[cc] = relu4(acc);
  }
}

// ---------------- CSR-lite build ----------------
__global__ void fill_csr_kernel(const int* __restrict__ esrc, const int* __restrict__ edst,
                                int* __restrict__ counts, int* __restrict__ buckets) {
  int e = blockIdx.x * 256 + threadIdx.x;
  if (e >= (NLVL - 1) * EPLE) return;
  int l = e / EPLE;
  int key = l * PN + edst[e];
  int pos = atomicAdd(&counts[key], 1);
  if (pos < CAP) buckets[(size_t)key * CAP + pos] = esrc[e];
}

// ---------------- weight prep: fp32 [K][N] -> bf16 [N][K] ----------------
__global__ void prep_w(const float* __restrict__ we, const float* __restrict__ mpw,
                       const float* __restrict__ nw0, const float* __restrict__ nww,
                       ushort* __restrict__ wet, ushort* __restrict__ mpt,
                       ushort* __restrict__ ne0t, ushort* __restrict__ nwt) {
  int i = blockIdx.x * 256 + threadIdx.x;
  if (i < 256 * 128) { int n = i >> 7, k = i & 127; wet[i] = f2b(we[k * 256 + n]); }
  if (i < 4 * 65536) { int mi = i >> 16, rr = i & 65535, n = rr >> 8, k = rr & 255;
                       mpt[i] = f2b(mpw[mi * 65536 + k * 256 + n]); }
  if (i < 256 * 512) { int n = i >> 9, k = i & 511; ne0t[i] = f2b(nw0[k * 256 + n]); }
  if (i < 3 * 65536) { int mi = i >> 16, rr = i & 65535, n = rr >> 8, k = rr & 255;
                       nwt[i] = f2b(nww[mi * 65536 + k * 256 + n]); }
}

// ---------------- embed: base = tanh(nf @ W_embed + b), MFMA ----------------
__global__ __launch_bounds__(256, 1) void embed_mfma(
    const float* __restrict__ nf, const ushort* __restrict__ wet,
    const float* __restrict__ be, float* __restrict__ out) {
  const int w = threadIdx.x >> 6, lane = threadIdx.x & 63;
  const int r = lane & 15, g = lane >> 4;
  const int row = blockIdx.x * 64 + w * 16 + r;
  const bool valid = row < NTOT;
  const int rl = valid ? row : 0;

  short8 B[4];
  #pragma unroll
  for (int kc = 0; kc < 4; ++kc) {
    float t[8];
    f32x4 a0 = *(const f32x4*)(nf + (size_t)rl * FDIM + kc * 32 + 8 * g);
    f32x4 a1 = *(const f32x4*)(nf + (size_t)rl * FDIM + kc * 32 + 8 * g + 4);
    t[0] = a0[0]; t[1] = a0[1]; t[2] = a0[2]; t[3] = a0[3];
    t[4] = a1[0]; t[5] = a1[1]; t[6] = a1[2]; t[7] = a1[3];
    B[kc] = pack8(t);
  }
  #pragma unroll
  for (int cc = 0; cc < 16; ++cc) {
    f32x4 acc = *(const f32x4*)(be + 16 * cc + 4 * g);
    #pragma unroll
    for (int kc = 0; kc < 4; ++kc)
      acc = mfma16(*(const short8*)(wet + (16 * cc + r) * FDIM + kc * 32 + 8 * g), B[kc], acc);
    if (valid) {
      f32x4 o;
      o[0] = tanhf(acc[0]); o[1] = tanhf(acc[1]); o[2] = tanhf(acc[2]); o[3] = tanhf(acc[3]);
      *(f32x4*)(out + (size_t)row * HDIM + 16 * cc + 4 * g) = o;
    }
  }
}

// ---------------- fused per-level chain, one 16-row strip per wave ----------
__global__ __launch_bounds__(256, 1) void level_mfma(
    float* __restrict__ eb,
    const int* __restrict__ counts, const int* __restrict__ buckets,
    const ushort* __restrict__ mpt, const float* __restrict__ mpb,
    const ushort* __restrict__ ne0t, const float* __restrict__ neb0,
    const ushort* __restrict__ nwt, const float* __restrict__ neb,
    int l) {
  __shared__ ushort act[4][4096];   // per-wave 8KB bf16 strip buffer
  const int w = threadIdx.x >> 6, lane = threadIdx.x & 63;
  const int r = lane & 15, g = lane >> 4;
  char* sb = (char*)act[w];
  const int p = blockIdx.x * 64 + w * 16 + r;
  const bool valid = p < PN;
  const int pe = valid ? p : 0;

  // ---- gather mailbox (segment sum) directly into B-frag slices, fp32 ----
  float m[8][8];
  #pragma unroll
  for (int kc = 0; kc < 8; ++kc)
    #pragma unroll
    for (int e = 0; e < 8; ++e) m[kc][e] = 0.f;
  if (valid) {
    int cnt = counts[l * PN + p]; cnt = cnt > CAP ? CAP : cnt;
    const int* bk = buckets + (size_t)(l * PN + p) * CAP;
    for (int j = 0; j < cnt; ++j) {
      const float* src = eb + (size_t)bk[j] * HDIM;
      #pragma unroll
      for (int kc = 0; kc < 8; ++kc) {
        f32x4 a0 = *(const f32x4*)(src + kc * 32 + 8 * g);
        f32x4 a1 = *(const f32x4*)(src + kc * 32 + 8 * g + 4);
        m[kc][0] += a0[0]; m[kc][1] += a0[1]; m[kc][2] += a0[2]; m[kc][3] += a0[3];
        m[kc][4] += a1[0]; m[kc][5] += a1[1]; m[kc][6] += a1[2]; m[kc][7] += a1[3];
      }
    }
  }
  short8 B[8];
  #pragma unroll
  for (int kc = 0; kc < 8; ++kc) B[kc] = pack8(m[kc]);

  f32x4 X[16], Y[16], Z[16];

  // ---- redux chain: t0, u1, u2, mr ----
  __syncthreads();
  stage<8>(mpt, 256, mpb, B, X, r, g);                       // X = t0
  w1(sb, r, g, X); rB(sb, r, g, B);
  __syncthreads();
  stage<8>(mpt + 65536, 256, mpb + 256, B, Y, r, g);         // Y = u1
  w2(sb, r, g, X, Y); rB(sb, r, g, B);
  __syncthreads();
  stage<8>(mpt + 131072, 256, mpb + 512, B, Z, r, g);        // Z = u2
  w2(sb, r, g, Y, Z); rB(sb, r, g, B);
  __syncthreads();
  stage<8>(mpt + 196608, 256, mpb + 768, B, X, r, g);        // X = mr

  // ---- apply: x0 = relu([base | mr] @ ne_w0 + b) ----
  short8 BB[16];
  const float* baseg = eb + (size_t)((l + 1) * PN + pe) * HDIM;
  #pragma unroll
  for (int kc = 0; kc < 8; ++kc) {
    float t[8];
    f32x4 a0 = *(const f32x4*)(baseg + kc * 32 + 8 * g);
    f32x4 a1 = *(const f32x4*)(baseg + kc * 32 + 8 * g + 4);
    t[0] = a0[0]; t[1] = a0[1]; t[2] = a0[2]; t[3] = a0[3];
    t[4] = a1[0]; t[5] = a1[1]; t[6] = a1[2]; t[7] = a1[3];
    BB[kc] = pack8(t);
  }
  w1(sb, r, g, X); rB(sb, r, g, B);                          // bf16(mr)
  #pragma unroll
  for (int kc = 0; kc < 8; ++kc) BB[8 + kc] = B[kc];
  __syncthreads();
  stage<16>(ne0t, 512, neb0, BB, Y, r, g);                   // Y = x0
  w1(sb, r, g, Y); rB(sb, r, g, B);
  __syncthreads();
  stage<8>(nwt, 256, neb, B, Z, r, g);                       // Z = v1
  w2(sb, r, g, Y, Z); rB(sb, r, g, B);
  __syncthreads();
  stage<8>(nwt + 65536, 256, neb + 256, B, X, r, g);         // X = v2
  w2(sb, r, g, Z, X); rB(sb, r, g, B);
  __syncthreads();
  stage<8>(nwt + 131072, 256, neb + 512, B, Y, r, g);        // Y = out

  if (valid) {
    float* og = eb + (size_t)((l + 1) * PN + p) * HDIM;
    #pragma unroll
    for (int cc = 0; cc < 16; ++cc)
      *(f32x4*)(og + 16 * cc + 4 * g) = Y[cc];
  }
}

// ---------------- launch ----------------
extern "C" void kernel_launch(void* const* d_in, const int* in_sizes, int n_in,
                              void* d_out, int out_size, void* d_ws, size_t ws_size,
                              hipStream_t stream) {
  (void)in_sizes; (void)n_in; (void)out_size; (void)ws_size;
  const float* nf      = (const float*)d_in[0];
  const float* W_embed = (const float*)d_in[1];
  const float* b_embed = (const float*)d_in[2];
  const float* mp_w    = (const float*)d_in[3];
  const float* mp_b    = (const float*)d_in[4];
  const float* ne_w0   = (const float*)d_in[5];
  const float* ne_b0   = (const float*)d_in[6];
  const float* ne_w    = (const float*)d_in[7];
  const float* ne_b    = (const float*)d_in[8];
  const int*   esrc    = (const int*)d_in[9];
  const int*   edst    = (const int*)d_in[10];
  float* out = (float*)d_out;

  int*    counts  = (int*)d_ws;                                 // 95000 ints
  int*    buckets = (int*)((char*)d_ws + (512 << 10));          // 95000*32 ints (~12.2MB)
  ushort* wet     = (ushort*)((char*)d_ws + (13u << 20));       // bf16 weights, transposed
  ushort* mpt     = wet + 256 * 128;
  ushort* ne0t    = mpt + 4 * 65536;
  ushort* nwt     = ne0t + 256 * 512;

  hipMemsetAsync(counts, 0, (NLVL - 1) * PN * sizeof(int), stream);
  fill_csr_kernel<<<((NLVL - 1) * EPLE + 255) / 256, 256, 0, stream>>>(esrc, edst, counts, buckets);
  prep_w<<<1024, 256, 0, stream>>>(W_embed, mp_w, ne_w0, ne_w, wet, mpt, ne0t, nwt);
  embed_mfma<<<(NTOT + 63) / 64, 256, 0, stream>>>(nf, wet, b_embed, out);
  for (int l = 0; l < NLVL - 1; ++l) {
    level_mfma<<<(PN + 63) / 64, 256, 0, stream>>>(out, counts, buckets,
                                                   mpt, mp_b, ne0t, ne_b0, nwt, ne_b, l);
  }
}

// Round 3
// 1595.675 us; speedup vs baseline: 2.5812x; 2.0618x over previous
//
#include <hip/hip_runtime.h>
#include <hip/hip_bf16.h>

#define NLVL 20
#define PN   5000
#define EPLE 40000
#define FDIM 128
#define HDIM 256
#define NTOT (NLVL * PN)
#define CAP  32

typedef __attribute__((ext_vector_type(8))) short short8;   // 8 bf16 in 4 VGPRs
typedef __attribute__((ext_vector_type(4))) float f32x4;

__device__ __forceinline__ f32x4 mfma16(short8 a, short8 b, f32x4 c) {
  return __builtin_amdgcn_mfma_f32_16x16x32_bf16(a, b, c, 0, 0, 0);
}

__device__ __forceinline__ ushort f2b(float f) {
  union { float f; unsigned u; } v; v.f = f;
  unsigned r = v.u + 0x7FFFu + ((v.u >> 16) & 1u);   // RNE
  return (ushort)(r >> 16);
}

__device__ __forceinline__ uint2 packu2(f32x4 v) {
  union { uint2 u2; ushort s[4]; } p;
  p.s[0] = f2b(v[0]); p.s[1] = f2b(v[1]); p.s[2] = f2b(v[2]); p.s[3] = f2b(v[3]);
  return p.u2;
}

__device__ __forceinline__ f32x4 relu4(f32x4 a) {
  f32x4 o;
  o[0] = fmaxf(a[0], 0.f); o[1] = fmaxf(a[1], 0.f);
  o[2] = fmaxf(a[2], 0.f); o[3] = fmaxf(a[3], 0.f);
  return o;
}

// ---- LDS: [16 rows][256 cols] bf16 per buffer, XOR-swizzled (T2-style) ----
__device__ __forceinline__ void st_lds8(ushort* buf, int r, int byteoff, uint2 v) {
  *(uint2*)((char*)buf + r * 512 + (byteoff ^ ((r & 7) << 4))) = v;
}
__device__ __forceinline__ short8 ld_lds16(const ushort* buf, int r, int byteoff) {
  return *(const short8*)((const char*)buf + r * 512 + (byteoff ^ ((r & 7) << 4)));
}
__device__ __forceinline__ void rdB(const ushort* buf, short8* B, int r, int g) {
  #pragma unroll
  for (int kc = 0; kc < 8; ++kc) B[kc] = ld_lds16(buf, r, 64 * kc + 16 * g);
}
__device__ __forceinline__ void wr2(ushort* buf, f32x4 a, f32x4 b, int cc0, int r, int g) {
  st_lds8(buf, r, 32 * cc0 + 8 * g, packu2(a));
  st_lds8(buf, r, 32 * (cc0 + 1) + 8 * g, packu2(b));
}
__device__ __forceinline__ void wr2add(ushort* buf, const f32x4* X, const f32x4* Y,
                                       int cc0, int r, int g) {
  st_lds8(buf, r, 32 * cc0 + 8 * g, packu2(X[0] + Y[0]));
  st_lds8(buf, r, 32 * (cc0 + 1) + 8 * g, packu2(X[1] + Y[1]));
}

// one wave computes 2 col-tiles (32 cols) of a stage; weights [N][K] bf16 from L2
template <int NK>
__device__ __forceinline__ void stg2(const ushort* __restrict__ Wt, int sK,
                                     const float* __restrict__ bias,
                                     const short8* B, f32x4* out, int cc0, int r, int g) {
  #pragma unroll
  for (int t = 0; t < 2; ++t) {
    const int cc = cc0 + t;
    f32x4 acc = *(const f32x4*)(bias + 16 * cc + 4 * g);
    #pragma unroll
    for (int kc = 0; kc < NK; ++kc)
      acc = mfma16(*(const short8*)(Wt + (size_t)(16 * cc + r) * sK + kc * 32 + 8 * g),
                   B[kc], acc);
    out[t] = relu4(acc);
  }
}

// ---------------- CSR-lite build ----------------
__global__ void fill_csr_kernel(const int* __restrict__ esrc, const int* __restrict__ edst,
                                int* __restrict__ counts, int* __restrict__ buckets) {
  int e = blockIdx.x * 256 + threadIdx.x;
  if (e >= (NLVL - 1) * EPLE) return;
  int l = e / EPLE;
  int key = l * PN + edst[e];
  int pos = atomicAdd(&counts[key], 1);
  if (pos < CAP) buckets[(size_t)key * CAP + pos] = esrc[e];
}

// ---------------- weight prep: fp32 [K][N] -> bf16 [N][K] ----------------
__global__ void prep_w(const float* __restrict__ we, const float* __restrict__ mpw,
                       const float* __restrict__ nw0, const float* __restrict__ nww,
                       ushort* __restrict__ wet, ushort* __restrict__ mpt,
                       ushort* __restrict__ ne0t, ushort* __restrict__ nwt) {
  int i = blockIdx.x * 256 + threadIdx.x;
  if (i < 256 * 128) { int n = i >> 7, k = i & 127; wet[i] = f2b(we[k * 256 + n]); }
  if (i < 4 * 65536) { int mi = i >> 16, rr = i & 65535, n = rr >> 8, k = rr & 255;
                       mpt[i] = f2b(mpw[mi * 65536 + k * 256 + n]); }
  if (i < 256 * 512) { int n = i >> 9, k = i & 511; ne0t[i] = f2b(nw0[k * 256 + n]); }
  if (i < 3 * 65536) { int mi = i >> 16, rr = i & 65535, n = rr >> 8, k = rr & 255;
                       nwt[i] = f2b(nww[mi * 65536 + k * 256 + n]); }
}

// ---------------- embed: base = tanh(nf @ W_embed + b), 32 rows/wave ----------
__global__ __launch_bounds__(256, 4) void embed_mfma(
    const float* __restrict__ nf, const ushort* __restrict__ wet,
    const float* __restrict__ be, float* __restrict__ out) {
  const int w = threadIdx.x >> 6, lane = threadIdx.x & 63;
  const int r = lane & 15, g = lane >> 4;
  const int rowa = blockIdx.x * 128 + w * 32 + r;
  const int rowb = rowa + 16;
  const int ra = rowa < NTOT ? rowa : 0;
  const int rb = rowb < NTOT ? rowb : 0;

  short8 Ba[4], Bb[4];
  #pragma unroll
  for (int kc = 0; kc < 4; ++kc) {
    float t[8];
    f32x4 a0 = *(const f32x4*)(nf + (size_t)ra * FDIM + kc * 32 + 8 * g);
    f32x4 a1 = *(const f32x4*)(nf + (size_t)ra * FDIM + kc * 32 + 8 * g + 4);
    t[0]=a0[0]; t[1]=a0[1]; t[2]=a0[2]; t[3]=a0[3];
    t[4]=a1[0]; t[5]=a1[1]; t[6]=a1[2]; t[7]=a1[3];
    short8 o; 
    #pragma unroll
    for (int i = 0; i < 8; ++i) o[i] = (short)f2b(t[i]);
    Ba[kc] = o;
    f32x4 b0 = *(const f32x4*)(nf + (size_t)rb * FDIM + kc * 32 + 8 * g);
    f32x4 b1 = *(const f32x4*)(nf + (size_t)rb * FDIM + kc * 32 + 8 * g + 4);
    t[0]=b0[0]; t[1]=b0[1]; t[2]=b0[2]; t[3]=b0[3];
    t[4]=b1[0]; t[5]=b1[1]; t[6]=b1[2]; t[7]=b1[3];
    #pragma unroll
    for (int i = 0; i < 8; ++i) o[i] = (short)f2b(t[i]);
    Bb[kc] = o;
  }
  #pragma unroll
  for (int cc = 0; cc < 16; ++cc) {
    f32x4 bias = *(const f32x4*)(be + 16 * cc + 4 * g);
    f32x4 aa = bias, ab = bias;
    #pragma unroll
    for (int kc = 0; kc < 4; ++kc) {
      short8 wv = *(const short8*)(wet + (size_t)(16 * cc + r) * FDIM + kc * 32 + 8 * g);
      aa = mfma16(wv, Ba[kc], aa);
      ab = mfma16(wv, Bb[kc], ab);
    }
    if (rowa < NTOT) {
      f32x4 o; o[0]=tanhf(aa[0]); o[1]=tanhf(aa[1]); o[2]=tanhf(aa[2]); o[3]=tanhf(aa[3]);
      *(f32x4*)(out + (size_t)rowa * HDIM + 16 * cc + 4 * g) = o;
    }
    if (rowb < NTOT) {
      f32x4 o; o[0]=tanhf(ab[0]); o[1]=tanhf(ab[1]); o[2]=tanhf(ab[2]); o[3]=tanhf(ab[3]);
      *(f32x4*)(out + (size_t)rowb * HDIM + 16 * cc + 4 * g) = o;
    }
  }
}

// ------- fused per-level chain: 16 rows/block, 8 waves split 256 cols -------
__global__ __launch_bounds__(512, 4) void level_mfma(
    float* __restrict__ eb,
    const int* __restrict__ counts, const int* __restrict__ buckets,
    const ushort* __restrict__ mpt, const float* __restrict__ mpb,
    const ushort* __restrict__ ne0t, const float* __restrict__ neb0,
    const ushort* __restrict__ nwt, const float* __restrict__ neb,
    int l) {
  __shared__ ushort Bs[3][16 * 256];
  __shared__ int cnt_s[16];
  const int tid = threadIdx.x, w = tid >> 6, lane = tid & 63;
  const int r = lane & 15, g = lane >> 4;
  const int p0 = blockIdx.x * 16;
  const int cc0 = 2 * w;

  if (tid < 16) {
    int p = p0 + tid;
    cnt_s[tid] = (p < PN) ? min(counts[l * PN + p], CAP) : 0;
  }
  __syncthreads();

  // ---- gather: wave w sums rows 2w, 2w+1 with whole-wave 1KB coalesced loads
  {
    const int r0 = 2 * w, r1 = r0 + 1;
    const int c0 = cnt_s[r0], c1 = cnt_s[r1];
    const int* bk0 = buckets + (size_t)(l * PN + (p0 + r0 < PN ? p0 + r0 : 0)) * CAP;
    const int* bk1 = buckets + (size_t)(l * PN + (p0 + r1 < PN ? p0 + r1 : 0)) * CAP;
    f32x4 s0 = {0,0,0,0}, s1 = {0,0,0,0};
    int mx = c0 > c1 ? c0 : c1;
    for (int j = 0; j < mx; ++j) {
      if (j < c0) s0 += *(const f32x4*)(eb + (size_t)bk0[j] * HDIM + 4 * lane);
      if (j < c1) s1 += *(const f32x4*)(eb + (size_t)bk1[j] * HDIM + 4 * lane);
    }
    st_lds8(Bs[0], r0, 8 * lane, packu2(s0));
    st_lds8(Bs[0], r1, 8 * lane, packu2(s1));
  }
  __syncthreads();

  short8 B[8];
  f32x4 X[2], Y[2], Z[2];

  rdB(Bs[0], B, r, g);
  stg2<8>(mpt, 256, mpb, B, X, cc0, r, g);                     // X = t0
  wr2(Bs[1], X[0], X[1], cc0, r, g);
  __syncthreads();

  rdB(Bs[1], B, r, g);
  stg2<8>(mpt + 65536, 256, mpb + 256, B, Y, cc0, r, g);       // Y = u1
  wr2add(Bs[2], X, Y, cc0, r, g);                              // t0+u1
  __syncthreads();

  rdB(Bs[2], B, r, g);
  stg2<8>(mpt + 131072, 256, mpb + 512, B, Z, cc0, r, g);      // Z = u2
  wr2add(Bs[0], Y, Z, cc0, r, g);                              // u1+u2
  __syncthreads();

  // issue base loads early (hide under S4 MFMAs)
  const int pr0 = (p0 + 2 * w)     < PN ? p0 + 2 * w     : PN - 1;
  const int pr1 = (p0 + 2 * w + 1) < PN ? p0 + 2 * w + 1 : PN - 1;
  f32x4 bs0 = *(const f32x4*)(eb + ((size_t)((l + 1) * PN) + pr0) * HDIM + 4 * lane);
  f32x4 bs1 = *(const f32x4*)(eb + ((size_t)((l + 1) * PN) + pr1) * HDIM + 4 * lane);

  rdB(Bs[0], B, r, g);
  stg2<8>(mpt + 196608, 256, mpb + 768, B, X, cc0, r, g);      // X = mr
  wr2(Bs[1], X[0], X[1], cc0, r, g);                           // mr   (Bs1 last read S2)
  st_lds8(Bs[2], 2 * w,     8 * lane, packu2(bs0));            // base (Bs2 last read S3)
  st_lds8(Bs[2], 2 * w + 1, 8 * lane, packu2(bs1));
  __syncthreads();

  {
    short8 BB[16];
    rdB(Bs[2], BB, r, g);                                      // base  -> K 0..255
    rdB(Bs[1], BB + 8, r, g);                                  // mr    -> K 256..511
    stg2<16>(ne0t, 512, neb0, BB, Y, cc0, r, g);               // Y = x0
  }
  wr2(Bs[0], Y[0], Y[1], cc0, r, g);                           // x0   (Bs0 last read S4)
  __syncthreads();

  rdB(Bs[0], B, r, g);
  stg2<8>(nwt, 256, neb, B, Z, cc0, r, g);                     // Z = v1
  wr2add(Bs[1], Y, Z, cc0, r, g);                              // x0+v1 (Bs1 last read S5)
  __syncthreads();

  rdB(Bs[1], B, r, g);
  stg2<8>(nwt + 65536, 256, neb + 256, B, X, cc0, r, g);       // X = v2
  wr2add(Bs[2], Z, X, cc0, r, g);                              // v1+v2 (Bs2 last read S5)
  __syncthreads();

  rdB(Bs[2], B, r, g);
  stg2<8>(nwt + 131072, 256, neb + 512, B, Y, cc0, r, g);      // Y = out
  if (p0 + r < PN) {
    float* og = eb + ((size_t)((l + 1) * PN) + p0 + r) * HDIM;
    *(f32x4*)(og + 16 * cc0 + 4 * g)       = Y[0];
    *(f32x4*)(og + 16 * (cc0 + 1) + 4 * g) = Y[1];
  }
}

// ---------------- launch ----------------
extern "C" void kernel_launch(void* const* d_in, const int* in_sizes, int n_in,
                              void* d_out, int out_size, void* d_ws, size_t ws_size,
                              hipStream_t stream) {
  (void)in_sizes; (void)n_in; (void)out_size; (void)ws_size;
  const float* nf      = (const float*)d_in[0];
  const float* W_embed = (const float*)d_in[1];
  const float* b_embed = (const float*)d_in[2];
  const float* mp_w    = (const float*)d_in[3];
  const float* mp_b    = (const float*)d_in[4];
  const float* ne_w0   = (const float*)d_in[5];
  const float* ne_b0   = (const float*)d_in[6];
  const float* ne_w    = (const float*)d_in[7];
  const float* ne_b    = (const float*)d_in[8];
  const int*   esrc    = (const int*)d_in[9];
  const int*   edst    = (const int*)d_in[10];
  float* out = (float*)d_out;

  int*    counts  = (int*)d_ws;                                 // 95000 ints
  int*    buckets = (int*)((char*)d_ws + (512 << 10));          // 95000*32 ints (~12.2MB)
  ushort* wet     = (ushort*)((char*)d_ws + (13u << 20));       // bf16 weights, transposed
  ushort* mpt     = wet + 256 * 128;
  ushort* ne0t    = mpt + 4 * 65536;
  ushort* nwt     = ne0t + 256 * 512;

  hipMemsetAsync(counts, 0, (NLVL - 1) * PN * sizeof(int), stream);
  fill_csr_kernel<<<((NLVL - 1) * EPLE + 255) / 256, 256, 0, stream>>>(esrc, edst, counts, buckets);
  prep_w<<<1024, 256, 0, stream>>>(W_embed, mp_w, ne_w0, ne_w, wet, mpt, ne0t, nwt);
  embed_mfma<<<(NTOT + 127) / 128, 256, 0, stream>>>(nf, wet, b_embed, out);
  for (int l = 0; l < NLVL - 1; ++l) {
    level_mfma<<<(PN + 15) / 16, 512, 0, stream>>>(out, counts, buckets,
                                                   mpt, mp_b, ne0t, ne_b0, nwt, ne_b, l);
  }
}